// Round 9
// baseline (233.653 us; speedup 1.0000x reference)
//
#include <hip/hip_runtime.h>
#include <hip/hip_fp16.h>

#define NN   100000
#define NE   1600000
#define CIN  128
#define CHID 128
#define COUT 64

// two-level CSR build
#define NPB  256                  // nodes per bucket (dst >> 8)
#define NB   391                  // ceil(NN / NPB)
#define NBLK 128                  // partition blocks
#define CHUNK ((NE + NBLK - 1) / NBLK)   // 12500
#define BPAD 2048                 // per-bucket padding slack (256 nodes * 8)

// MFMA types
typedef _Float16 f16x8 __attribute__((ext_vector_type(8)));
typedef float    f32x4 __attribute__((ext_vector_type(4)));

#define NTILE 782   // ceil(NN/128)
#define GGRID 512
#define G1B   384   // gemm1-role blocks in fused launch

// ---------------- fused: passA (blocks 0..127) + GEMM1 (blocks 128..511) ---
// passA: per-(bucket,block) histogram, identical pattern to the proven k_passA.
// GEMM1: H1[N,128] = f16(X @ W1) UNSCALED (dinv applied in agg1), 8 waves,
// wave tile = 16 rows x 128 cols, persistent over tiles.
__global__ __launch_bounds__(512) void k_pag1(const int* __restrict__ dst,
                                              int* __restrict__ tab,
                                              const float* __restrict__ X,
                                              const float* __restrict__ W,
                                              __half* __restrict__ G) {
  __shared__ int hist[NB];            // passA role (1.6 KB)
  __shared__ _Float16 Wt[128][128];   // gemm role (32 KB)
  int tid = threadIdx.x;
  int bid = blockIdx.x;

  if (bid < NBLK) {
    // ---- passA role (identical to R5 k_passA) ----
    for (int t = tid; t < NB; t += 512) hist[t] = 0;
    __syncthreads();
    int i0 = bid * CHUNK;
    int i1 = min(i0 + CHUNK, NE);
    for (int i = i0 + tid; i < i1; i += 512)
      atomicAdd(&hist[((unsigned)dst[i]) >> 8], 1);
    __syncthreads();
    for (int t = tid; t < NB; t += 512)
      tab[t * NBLK + bid] = hist[t];
    return;
  }

  // ---- GEMM1 role ----
  for (int i = tid; i < 128 * 32; i += 512) {
    int k = i >> 5, c4 = (i & 31) << 2;
    float4 v = ((const float4*)W)[i];
    Wt[c4 + 0][k] = (_Float16)v.x;
    Wt[c4 + 1][k] = (_Float16)v.y;
    Wt[c4 + 2][k] = (_Float16)v.z;
    Wt[c4 + 3][k] = (_Float16)v.w;
  }
  __syncthreads();
  int wv = tid >> 6, lane = tid & 63;
  int l15 = lane & 15, g = lane >> 4;

  f16x8 wf[8][4];
#pragma unroll
  for (int cf = 0; cf < 8; cf++)
#pragma unroll
    for (int ks = 0; ks < 4; ks++)
      wf[cf][ks] = *(const f16x8*)&Wt[cf * 16 + l15][ks * 32 + g * 8];

  for (int t = bid - NBLK; t < NTILE; t += G1B) {
    int rowbase = t * 128 + wv * 16;
    f32x4 acc[8];
#pragma unroll
    for (int j = 0; j < 8; j++) acc[j] = (f32x4){0.f, 0.f, 0.f, 0.f};

    int r0 = min(rowbase + l15, NN - 1);
    const float* p0 = X + (size_t)r0 * CIN + g * 8;
    float4 u0a = *(const float4*)p0, u0b = *(const float4*)(p0 + 4);

#pragma unroll
    for (int ks = 0; ks < 4; ks++) {
      f16x8 xa;
      xa[0] = (_Float16)u0a.x; xa[1] = (_Float16)u0a.y;
      xa[2] = (_Float16)u0a.z; xa[3] = (_Float16)u0a.w;
      xa[4] = (_Float16)u0b.x; xa[5] = (_Float16)u0b.y;
      xa[6] = (_Float16)u0b.z; xa[7] = (_Float16)u0b.w;
      if (ks < 3) {
        int o = (ks + 1) * 32;
        u0a = *(const float4*)(p0 + o); u0b = *(const float4*)(p0 + o + 4);
      }
#pragma unroll
      for (int cf = 0; cf < 8; cf++)
        acc[cf] = __builtin_amdgcn_mfma_f32_16x16x32_f16(wf[cf][ks], xa, acc[cf], 0, 0, 0);
    }

    int row = rowbase + l15;
    if (row < NN) {
#pragma unroll
      for (int cf = 0; cf < 8; cf++) {
        int col = cf * 16 + g * 4;
        __half2 h0 = __half2(__float2half(acc[cf][0]), __float2half(acc[cf][1]));
        __half2 h1 = __half2(__float2half(acc[cf][2]), __float2half(acc[cf][3]));
        uint2 s;
        s.x = *(unsigned*)&h0;
        s.y = *(unsigned*)&h1;
        *(uint2*)(G + (size_t)row * CHID + col) = s;
      }
    }
  }
}

// ---------------- scan: bucket totals + per-bucket block offsets -----------
__global__ __launch_bounds__(512) void k_scan(int* __restrict__ tab,
                                              int* __restrict__ bb) {
  __shared__ int s[512];
  int t = threadIdx.x;
  int v = 0;
  if (t < NB) {
    const int* row = tab + t * NBLK;
#pragma unroll 8
    for (int k = 0; k < NBLK; k++) v += row[k];
  }
  s[t] = v;
  __syncthreads();
  for (int off = 1; off < 512; off <<= 1) {
    int u = (t >= off) ? s[t - off] : 0;
    __syncthreads();
    s[t] += u;
    __syncthreads();
  }
  int base = s[t] - v;     // exclusive bucket base
  if (t < NB) bb[t] = base;
  if (t == 0) bb[NB] = NE;
  if (t < NB) {
    int run = base;
    int* row = tab + t * NBLK;
    for (int k = 0; k < NBLK; k += 4) {
      int4 c = *(int4*)(row + k);
      int4 w;
      w.x = run; run += c.x;
      w.y = run; run += c.y;
      w.z = run; run += c.z;
      w.w = run; run += c.w;
      *(int4*)(row + k) = w;
    }
  }
}

// ---------------- pass B: scatter edges into bucket array ----------------
__global__ __launch_bounds__(512) void k_passB(const int* __restrict__ src,
                                               const int* __restrict__ dst,
                                               const int* __restrict__ tab,
                                               int* __restrict__ barr) {
  __shared__ int cur[NB];
  int tid = threadIdx.x;
  for (int t = tid; t < NB; t += 512) cur[t] = tab[t * NBLK + blockIdx.x];
  __syncthreads();
  int i0 = blockIdx.x * CHUNK;
  int i1 = min(i0 + CHUNK, NE);
  for (int i = i0 + tid; i < i1; i += 512) {
    int d = dst[i];
    unsigned b = ((unsigned)d) >> 8;
    int p = atomicAdd(&cur[b], 1);
    barr[p] = (src[i] << 8) | (d & 255);
  }
}

// ---------------- level 2: padded csr, rs, re, dinv, sentinels -------------
__global__ __launch_bounds__(256) void k_l2(const int* __restrict__ barr,
                                            const int* __restrict__ bb,
                                            int* __restrict__ csr,
                                            int* __restrict__ rs,
                                            int* __restrict__ re,
                                            float* __restrict__ dinv,
                                            __half* __restrict__ g1,
                                            __half* __restrict__ g2) {
  __shared__ int lcnt[NPB];
  __shared__ int lcur[NPB];
  int b = blockIdx.x, t = threadIdx.x;
  if (b == 0) {   // sentinel zero rows + dinv sentinel
    if (t < 128) g1[(size_t)NN * CHID + t] = __float2half(0.f);
    if (t < 64)  g2[(size_t)NN * COUT + t] = __float2half(0.f);
    if (t == 0)  dinv[NN] = 0.f;
  }
  int e0 = bb[b], e1 = bb[b + 1];
  lcnt[t] = 0;
  __syncthreads();
  for (int i = e0 + t; i < e1; i += 256) atomicAdd(&lcnt[barr[i] & 255], 1);
  __syncthreads();
  int v = lcnt[t];
  int pv = (v + 7) & ~7;          // padded count
  lcur[t] = pv;
  __syncthreads();
  for (int off = 1; off < 256; off <<= 1) {
    int u = (t >= off) ? lcur[t - off] : 0;
    __syncthreads();
    lcur[t] += u;
    __syncthreads();
  }
  int pex = lcur[t] - pv;
  int start = e0 + b * BPAD + pex;
  int g = b * NPB + t;
  if (g < NN) {
    rs[g] = start;
    re[g] = start + pv;
    dinv[g] = rsqrtf((float)v + 1.0f);
  }
  __syncthreads();
  lcur[t] = start;
  for (int k = v; k < pv; k++) csr[start + k] = NN;
  __syncthreads();
  for (int i = e0 + t; i < e1; i += 256) {
    int w = barr[i];
    int p = atomicAdd(&lcur[w & 255], 1);
    csr[p] = ((unsigned)w) >> 8;
  }
}

// ---------------- GEMM 2 (MFMA f16): G2[N,64] = f16(dinv*(O1 @ W2)) --------
__global__ __launch_bounds__(256, 2) void k_gemm2(const __half* __restrict__ X,
                                                  const float* __restrict__ W,
                                                  const float* __restrict__ dinv,
                                                  __half* __restrict__ G) {
  __shared__ _Float16 Wt[64][128];    // [col][k], 16 KB
  int tid = threadIdx.x;
  for (int i = tid; i < 128 * 16; i += 256) {
    int k = i >> 4, c4 = (i & 15) << 2;
    float4 v = ((const float4*)W)[i];
    Wt[c4 + 0][k] = (_Float16)v.x;
    Wt[c4 + 1][k] = (_Float16)v.y;
    Wt[c4 + 2][k] = (_Float16)v.z;
    Wt[c4 + 3][k] = (_Float16)v.w;
  }
  __syncthreads();
  int wv = tid >> 6, lane = tid & 63;
  int l15 = lane & 15, g = lane >> 4;

  f16x8 wf[4][4];
#pragma unroll
  for (int cf = 0; cf < 4; cf++)
#pragma unroll
    for (int ks = 0; ks < 4; ks++)
      wf[cf][ks] = *(const f16x8*)&Wt[cf * 16 + l15][ks * 32 + g * 8];

  for (int t = blockIdx.x; t < NTILE; t += GGRID) {
    int rowbase = t * 128 + wv * 32;
    f32x4 acc[2][4];
#pragma unroll
    for (int i = 0; i < 2; i++)
#pragma unroll
      for (int j = 0; j < 4; j++) acc[i][j] = (f32x4){0.f, 0.f, 0.f, 0.f};

    int r0 = min(rowbase + l15, NN - 1);
    int r1 = min(rowbase + 16 + l15, NN - 1);
    const _Float16* p0 = (const _Float16*)X + (size_t)r0 * CHID + g * 8;
    const _Float16* p1 = (const _Float16*)X + (size_t)r1 * CHID + g * 8;

    f16x8 xa = *(const f16x8*)p0;
    f16x8 xb = *(const f16x8*)p1;

#pragma unroll
    for (int ks = 0; ks < 4; ks++) {
      f16x8 ca = xa, cb = xb;
      if (ks < 3) {
        int o = (ks + 1) * 32;
        xa = *(const f16x8*)(p0 + o);
        xb = *(const f16x8*)(p1 + o);
      }
#pragma unroll
      for (int cf = 0; cf < 4; cf++) {
        acc[0][cf] = __builtin_amdgcn_mfma_f32_16x16x32_f16(wf[cf][ks], ca, acc[0][cf], 0, 0, 0);
        acc[1][cf] = __builtin_amdgcn_mfma_f32_16x16x32_f16(wf[cf][ks], cb, acc[1][cf], 0, 0, 0);
      }
    }

#pragma unroll
    for (int rf = 0; rf < 2; rf++) {
      int row = rowbase + rf * 16 + l15;
      if (row < NN) {
        float dn = dinv[row];
#pragma unroll
        for (int cf = 0; cf < 4; cf++) {
          int col = cf * 16 + g * 4;
          __half2 h0 = __half2(__float2half(dn * acc[rf][cf][0]),
                               __float2half(dn * acc[rf][cf][1]));
          __half2 h1 = __half2(__float2half(dn * acc[rf][cf][2]),
                               __float2half(dn * acc[rf][cf][3]));
          uint2 s;
          s.x = *(unsigned*)&h0;
          s.y = *(unsigned*)&h1;
          *(uint2*)(G + (size_t)row * COUT + col) = s;
        }
      }
    }
  }
}

// accumulate 8 f16 channels (uint4) into 8 f32 (plain add)
#define ACC8(A, V)                                                  \
  {                                                                 \
    float2 f;                                                       \
    f = __half22float2(*(__half2*)&(V).x); A[0] += f.x; A[1] += f.y; \
    f = __half22float2(*(__half2*)&(V).y); A[2] += f.x; A[3] += f.y; \
    f = __half22float2(*(__half2*)&(V).z); A[4] += f.x; A[5] += f.y; \
    f = __half22float2(*(__half2*)&(V).w); A[6] += f.x; A[7] += f.y; \
  }

// accumulate 8 f16 channels (uint4) into 8 f32, scaled by D (fma)
#define ACC8F(A, V, D)                                                        \
  {                                                                           \
    float2 f;                                                                 \
    f = __half22float2(*(__half2*)&(V).x); A[0] = fmaf(D, f.x, A[0]); A[1] = fmaf(D, f.y, A[1]); \
    f = __half22float2(*(__half2*)&(V).y); A[2] = fmaf(D, f.x, A[2]); A[3] = fmaf(D, f.y, A[3]); \
    f = __half22float2(*(__half2*)&(V).z); A[4] = fmaf(D, f.x, A[4]); A[5] = fmaf(D, f.y, A[5]); \
    f = __half22float2(*(__half2*)&(V).w); A[6] = fmaf(D, f.x, A[6]); A[7] = fmaf(D, f.y, A[7]); \
  }

// ---------------- aggregation layer 1 (quarters of 16 lanes) ----------------
// R5-proven structure (2 gathers in flight); g = UNSCALED h1, per-edge
// dinv[src] applied via fma (R6-proven, 66.4us).
__global__ __launch_bounds__(256) void k_agg1(const __half* __restrict__ g,
                                              const int* __restrict__ rs,
                                              const int* __restrict__ re,
                                              const float* __restrict__ dinv,
                                              const int* __restrict__ csr,
                                              const float* __restrict__ b,
                                              __half* __restrict__ o) {
  int wid = (blockIdx.x * blockDim.x + threadIdx.x) >> 6;
  int lane = threadIdx.x & 63;
  if (wid >= NN) return;
  int q = lane >> 4, ql = lane & 15;
  const uint4* gp = (const uint4*)g;   // row = 16 uint4

  float aA[8] = {0.f, 0.f, 0.f, 0.f, 0.f, 0.f, 0.f, 0.f};
  float aB[8] = {0.f, 0.f, 0.f, 0.f, 0.f, 0.f, 0.f, 0.f};

  float dnw = dinv[wid];
  if (q == 0) {                         // self row: dinv[wid]*h[wid]
    uint4 v = gp[(size_t)wid * 16 + ql];
    ACC8F(aA, v, dnw);
  }

  int i0 = rs[wid], i1 = re[wid];       // padded range, multiple of 8
  for (int i = i0; i < i1; i += 8) {
    int sA = csr[i + q];                // 16-lane broadcast
    int sB = csr[i + 4 + q];
    float dA = dinv[sA];                // L2-resident broadcast
    float dB = dinv[sB];
    uint4 vA = gp[(size_t)sA * 16 + ql];
    uint4 vB = gp[(size_t)sB * 16 + ql];
    ACC8F(aA, vA, dA);
    ACC8F(aB, vB, dB);
  }

  float r[8];
#pragma unroll
  for (int c = 0; c < 8; c++) {
    float t = aA[c] + aB[c];
    t += __shfl_xor(t, 16);
    t += __shfl_xor(t, 32);
    r[c] = t;
  }
  if (q == 0) {
    float4 b0 = *(const float4*)(b + 8 * ql);
    float4 b1 = *(const float4*)(b + 8 * ql + 4);
    __half2 h[4];
    h[0] = __half2(__float2half(fmaxf(fmaf(dnw, r[0], b0.x), 0.f)),
                   __float2half(fmaxf(fmaf(dnw, r[1], b0.y), 0.f)));
    h[1] = __half2(__float2half(fmaxf(fmaf(dnw, r[2], b0.z), 0.f)),
                   __float2half(fmaxf(fmaf(dnw, r[3], b0.w), 0.f)));
    h[2] = __half2(__float2half(fmaxf(fmaf(dnw, r[4], b1.x), 0.f)),
                   __float2half(fmaxf(fmaf(dnw, r[5], b1.y), 0.f)));
    h[3] = __half2(__float2half(fmaxf(fmaf(dnw, r[6], b1.z), 0.f)),
                   __float2half(fmaxf(fmaf(dnw, r[7], b1.w), 0.f)));
    *(uint4*)(o + (size_t)wid * CHID + 8 * ql) = *(uint4*)h;
  }
}

// ---------------- aggregation layer 2 (eighths of 8 lanes, R5-exact) -------
__global__ __launch_bounds__(256) void k_agg2(const __half* __restrict__ g,
                                              const int* __restrict__ rs,
                                              const int* __restrict__ re,
                                              const float* __restrict__ dinv,
                                              const int* __restrict__ csr,
                                              const float* __restrict__ b,
                                              float* __restrict__ o) {
  int wid = (blockIdx.x * blockDim.x + threadIdx.x) >> 6;
  int lane = threadIdx.x & 63;
  if (wid >= NN) return;
  int g8 = lane >> 3, gl = lane & 7;
  const uint4* gp = (const uint4*)g;   // row = 8 uint4

  float aA[8] = {0.f, 0.f, 0.f, 0.f, 0.f, 0.f, 0.f, 0.f};

  if (g8 == 0) {                        // self row (g2 pre-scaled)
    uint4 v = gp[(size_t)wid * 8 + gl];
    ACC8(aA, v);
  }

  int i0 = rs[wid], i1 = re[wid];       // padded range, multiple of 8
  for (int i = i0; i < i1; i += 8) {
    int s = csr[i + g8];                // 8-lane broadcast
    uint4 v = gp[(size_t)s * 8 + gl];
    ACC8(aA, v);
  }

  float r[8];
#pragma unroll
  for (int c = 0; c < 8; c++) {
    float t = aA[c];
    t += __shfl_xor(t, 8);
    t += __shfl_xor(t, 16);
    t += __shfl_xor(t, 32);
    r[c] = t;
  }
  if (g8 == 0) {
    float dn = dinv[wid];
    float4 b0 = *(const float4*)(b + 8 * gl);
    float4 b1 = *(const float4*)(b + 8 * gl + 4);
    float4 o0 = make_float4(fmaf(dn, r[0], b0.x), fmaf(dn, r[1], b0.y),
                            fmaf(dn, r[2], b0.z), fmaf(dn, r[3], b0.w));
    float4 o1v = make_float4(fmaf(dn, r[4], b1.x), fmaf(dn, r[5], b1.y),
                             fmaf(dn, r[6], b1.z), fmaf(dn, r[7], b1.w));
    *(float4*)(o + (size_t)wid * COUT + 8 * gl) = o0;
    *(float4*)(o + (size_t)wid * COUT + 8 * gl + 4) = o1v;
  }
}

// ---------------- launch ----------------

extern "C" void kernel_launch(void* const* d_in, const int* in_sizes, int n_in,
                              void* d_out, int out_size, void* d_ws, size_t ws_size,
                              hipStream_t stream) {
  const float* x  = (const float*)d_in[0];
  const int*   ei = (const int*)d_in[1];
  const float* W1 = (const float*)d_in[2];
  const float* b1 = (const float*)d_in[3];
  const float* W2 = (const float*)d_in[4];
  const float* b2 = (const float*)d_in[5];
  float* out = (float*)d_out;

  const int* esrc = ei;
  const int* edst = ei + NE;

  char* p = (char*)d_ws;
  __half* g1 = (__half*)p;    p += (size_t)(NN + 1) * CHID * 2;  // +zero row
  __half* o1 = (__half*)p;    p += (size_t)NN * CHID * 2;
  __half* g2 = (__half*)p;    p += (size_t)(NN + 1) * COUT * 2;  // +zero row
  int* rs  = (int*)p;         p += (size_t)NN * 4;
  int* re  = (int*)p;         p += (size_t)NN * 4;
  float* dinv = (float*)p;    p += (size_t)(NN + 1) * 4;         // +sentinel
  int* tab = (int*)p;         p += (size_t)NB * NBLK * 4;        // 200 KB
  int* bb  = (int*)p;         p += (size_t)(NB + 1) * 4;
  int* barr = (int*)p;        p += (size_t)NE * 4;               // 6.4 MB
  int* csr = (int*)p;         p += (size_t)(NE + NB * BPAD) * 4; // 9.6 MB

  // [passA || gemm1] -> scan -> passB -> l2 -> agg1 -> gemm2 -> agg2
  hipLaunchKernelGGL(k_pag1, dim3(NBLK + G1B), dim3(512), 0, stream,
                     edst, tab, x, W1, g1);
  hipLaunchKernelGGL(k_scan, dim3(1), dim3(512), 0, stream, tab, bb);
  hipLaunchKernelGGL(k_passB, dim3(NBLK), dim3(512), 0, stream, esrc, edst, tab, barr);
  hipLaunchKernelGGL(k_l2, dim3(NB), dim3(256), 0, stream, barr, bb, csr, rs, re,
                     dinv, g1, g2);

  hipLaunchKernelGGL(k_agg1, dim3((NN + 3) / 4), dim3(256), 0, stream,
                     g1, rs, re, dinv, csr, b1, o1);

  hipLaunchKernelGGL(k_gemm2, dim3(GGRID), dim3(256), 0, stream, o1, W2, dinv, g2);
  hipLaunchKernelGGL(k_agg2, dim3((NN + 3) / 4), dim3(256), 0, stream,
                     g2, rs, re, dinv, csr, b2, out);
}

// Round 10
// 231.308 us; speedup vs baseline: 1.0101x; 1.0101x over previous
//
#include <hip/hip_runtime.h>
#include <hip/hip_fp16.h>

#define NN   100000
#define NE   1600000
#define CIN  128
#define CHID 128
#define COUT 64

// two-level CSR build
#define NPB  256                  // nodes per bucket (dst >> 8)
#define NB   391                  // ceil(NN / NPB)
#define NBLK 128                  // partition blocks
#define CHUNK ((NE + NBLK - 1) / NBLK)   // 12500
#define BPAD 2048                 // per-bucket padding slack (256 nodes * 8)

// MFMA types
typedef _Float16 f16x8 __attribute__((ext_vector_type(8)));
typedef float    f32x4 __attribute__((ext_vector_type(4)));

#define NTILE 782   // ceil(NN/128)
#define GGRID 512

// ---------------- pass A: per-(bucket,block) histogram ----------------
__global__ __launch_bounds__(512) void k_passA(const int* __restrict__ dst,
                                               int* __restrict__ tab) {
  __shared__ int hist[NB];
  int tid = threadIdx.x;
  for (int t = tid; t < NB; t += 512) hist[t] = 0;
  __syncthreads();
  int i0 = blockIdx.x * CHUNK;
  int i1 = min(i0 + CHUNK, NE);
  for (int i = i0 + tid; i < i1; i += 512)
    atomicAdd(&hist[((unsigned)dst[i]) >> 8], 1);
  __syncthreads();
  for (int t = tid; t < NB; t += 512)
    tab[t * NBLK + blockIdx.x] = hist[t];
}

// ---------------- scan: bucket totals + per-bucket block offsets -----------
__global__ __launch_bounds__(512) void k_scan(int* __restrict__ tab,
                                              int* __restrict__ bb) {
  __shared__ int s[512];
  int t = threadIdx.x;
  int v = 0;
  if (t < NB) {
    const int* row = tab + t * NBLK;
#pragma unroll 8
    for (int k = 0; k < NBLK; k++) v += row[k];
  }
  s[t] = v;
  __syncthreads();
  for (int off = 1; off < 512; off <<= 1) {
    int u = (t >= off) ? s[t - off] : 0;
    __syncthreads();
    s[t] += u;
    __syncthreads();
  }
  int base = s[t] - v;     // exclusive bucket base
  if (t < NB) bb[t] = base;
  if (t == 0) bb[NB] = NE;
  if (t < NB) {
    int run = base;
    int* row = tab + t * NBLK;
    for (int k = 0; k < NBLK; k += 4) {
      int4 c = *(int4*)(row + k);
      int4 w;
      w.x = run; run += c.x;
      w.y = run; run += c.y;
      w.z = run; run += c.z;
      w.w = run; run += c.w;
      *(int4*)(row + k) = w;
    }
  }
}

// ---------------- pass B: scatter edges into bucket array ----------------
// entry = (src << 8) | (dst & 255);  src < 2^17 so this fits 25 bits
__global__ __launch_bounds__(512) void k_passB(const int* __restrict__ src,
                                               const int* __restrict__ dst,
                                               const int* __restrict__ tab,
                                               int* __restrict__ barr) {
  __shared__ int cur[NB];
  int tid = threadIdx.x;
  for (int t = tid; t < NB; t += 512) cur[t] = tab[t * NBLK + blockIdx.x];
  __syncthreads();
  int i0 = blockIdx.x * CHUNK;
  int i1 = min(i0 + CHUNK, NE);
  for (int i = i0 + tid; i < i1; i += 512) {
    int d = dst[i];
    unsigned b = ((unsigned)d) >> 8;
    int p = atomicAdd(&cur[b], 1);
    barr[p] = (src[i] << 8) | (d & 255);
  }
}

// ---------------- level 2: padded csr, rs, re, dinv, sentinels -------------
__global__ __launch_bounds__(256) void k_l2(const int* __restrict__ barr,
                                            const int* __restrict__ bb,
                                            int* __restrict__ csr,
                                            int* __restrict__ rs,
                                            int* __restrict__ re,
                                            float* __restrict__ dinv,
                                            __half* __restrict__ g1,
                                            __half* __restrict__ g2) {
  __shared__ int lcnt[NPB];
  __shared__ int lcur[NPB];
  int b = blockIdx.x, t = threadIdx.x;
  if (b == 0) {   // sentinel zero rows
    if (t < 128) g1[(size_t)NN * CHID + t] = __float2half(0.f);
    if (t < 64)  g2[(size_t)NN * COUT + t] = __float2half(0.f);
  }
  int e0 = bb[b], e1 = bb[b + 1];
  lcnt[t] = 0;
  __syncthreads();
  for (int i = e0 + t; i < e1; i += 256) atomicAdd(&lcnt[barr[i] & 255], 1);
  __syncthreads();
  int v = lcnt[t];
  int pv = (v + 7) & ~7;          // padded count
  lcur[t] = pv;
  __syncthreads();
  for (int off = 1; off < 256; off <<= 1) {
    int u = (t >= off) ? lcur[t - off] : 0;
    __syncthreads();
    lcur[t] += u;
    __syncthreads();
  }
  int pex = lcur[t] - pv;
  int start = e0 + b * BPAD + pex;
  int g = b * NPB + t;
  if (g < NN) {
    rs[g] = start;
    re[g] = start + pv;
    dinv[g] = rsqrtf((float)v + 1.0f);
  }
  __syncthreads();
  lcur[t] = start;
  for (int k = v; k < pv; k++) csr[start + k] = NN;
  __syncthreads();
  for (int i = e0 + t; i < e1; i += 256) {
    int w = barr[i];
    int p = atomicAdd(&lcur[w & 255], 1);
    csr[p] = ((unsigned)w) >> 8;
  }
}

// ---------------- GEMM 1 (MFMA f16): G1[N,128] = f16(dinv*(X @ W1)) --------
__global__ __launch_bounds__(256, 2) void k_gemm1(const float* __restrict__ X,
                                                  const float* __restrict__ W,
                                                  const float* __restrict__ dinv,
                                                  __half* __restrict__ G) {
  __shared__ _Float16 Wt[128][128];   // [col][k], 32 KB
  int tid = threadIdx.x;
  for (int i = tid; i < 128 * 32; i += 256) {
    int k = i >> 5, c4 = (i & 31) << 2;
    float4 v = ((const float4*)W)[i];
    Wt[c4 + 0][k] = (_Float16)v.x;
    Wt[c4 + 1][k] = (_Float16)v.y;
    Wt[c4 + 2][k] = (_Float16)v.z;
    Wt[c4 + 3][k] = (_Float16)v.w;
  }
  __syncthreads();
  int wv = tid >> 6, lane = tid & 63;
  int l15 = lane & 15, g = lane >> 4;

  f16x8 wf[8][4];
#pragma unroll
  for (int cf = 0; cf < 8; cf++)
#pragma unroll
    for (int ks = 0; ks < 4; ks++)
      wf[cf][ks] = *(const f16x8*)&Wt[cf * 16 + l15][ks * 32 + g * 8];

  for (int t = blockIdx.x; t < NTILE; t += GGRID) {
    int rowbase = t * 128 + wv * 32;
    f32x4 acc[2][8];
#pragma unroll
    for (int i = 0; i < 2; i++)
#pragma unroll
      for (int j = 0; j < 8; j++) acc[i][j] = (f32x4){0.f, 0.f, 0.f, 0.f};

    int r0 = min(rowbase + l15, NN - 1);
    int r1 = min(rowbase + 16 + l15, NN - 1);
    const float* p0 = X + (size_t)r0 * CIN + g * 8;
    const float* p1 = X + (size_t)r1 * CIN + g * 8;

    float4 u0a = *(const float4*)p0, u0b = *(const float4*)(p0 + 4);
    float4 u1a = *(const float4*)p1, u1b = *(const float4*)(p1 + 4);

#pragma unroll
    for (int ks = 0; ks < 4; ks++) {
      f16x8 xa, xb;
      xa[0] = (_Float16)u0a.x; xa[1] = (_Float16)u0a.y;
      xa[2] = (_Float16)u0a.z; xa[3] = (_Float16)u0a.w;
      xa[4] = (_Float16)u0b.x; xa[5] = (_Float16)u0b.y;
      xa[6] = (_Float16)u0b.z; xa[7] = (_Float16)u0b.w;
      xb[0] = (_Float16)u1a.x; xb[1] = (_Float16)u1a.y;
      xb[2] = (_Float16)u1a.z; xb[3] = (_Float16)u1a.w;
      xb[4] = (_Float16)u1b.x; xb[5] = (_Float16)u1b.y;
      xb[6] = (_Float16)u1b.z; xb[7] = (_Float16)u1b.w;
      if (ks < 3) {
        int o = (ks + 1) * 32;
        u0a = *(const float4*)(p0 + o); u0b = *(const float4*)(p0 + o + 4);
        u1a = *(const float4*)(p1 + o); u1b = *(const float4*)(p1 + o + 4);
      }
#pragma unroll
      for (int cf = 0; cf < 8; cf++) {
        acc[0][cf] = __builtin_amdgcn_mfma_f32_16x16x32_f16(wf[cf][ks], xa, acc[0][cf], 0, 0, 0);
        acc[1][cf] = __builtin_amdgcn_mfma_f32_16x16x32_f16(wf[cf][ks], xb, acc[1][cf], 0, 0, 0);
      }
    }

#pragma unroll
    for (int rf = 0; rf < 2; rf++) {
      int row = rowbase + rf * 16 + l15;
      if (row < NN) {
        float dn = dinv[row];
#pragma unroll
        for (int cf = 0; cf < 8; cf++) {
          int col = cf * 16 + g * 4;
          __half2 h0 = __half2(__float2half(dn * acc[rf][cf][0]),
                               __float2half(dn * acc[rf][cf][1]));
          __half2 h1 = __half2(__float2half(dn * acc[rf][cf][2]),
                               __float2half(dn * acc[rf][cf][3]));
          uint2 s;
          s.x = *(unsigned*)&h0;
          s.y = *(unsigned*)&h1;
          *(uint2*)(G + (size_t)row * CHID + col) = s;
        }
      }
    }
  }
}

// ---------------- GEMM 2 (MFMA f16): G2[N,64] = f16(dinv*(O1 @ W2)) --------
__global__ __launch_bounds__(256, 2) void k_gemm2(const __half* __restrict__ X,
                                                  const float* __restrict__ W,
                                                  const float* __restrict__ dinv,
                                                  __half* __restrict__ G) {
  __shared__ _Float16 Wt[64][128];    // [col][k], 16 KB
  int tid = threadIdx.x;
  for (int i = tid; i < 128 * 16; i += 256) {
    int k = i >> 4, c4 = (i & 15) << 2;
    float4 v = ((const float4*)W)[i];
    Wt[c4 + 0][k] = (_Float16)v.x;
    Wt[c4 + 1][k] = (_Float16)v.y;
    Wt[c4 + 2][k] = (_Float16)v.z;
    Wt[c4 + 3][k] = (_Float16)v.w;
  }
  __syncthreads();
  int wv = tid >> 6, lane = tid & 63;
  int l15 = lane & 15, g = lane >> 4;

  f16x8 wf[4][4];
#pragma unroll
  for (int cf = 0; cf < 4; cf++)
#pragma unroll
    for (int ks = 0; ks < 4; ks++)
      wf[cf][ks] = *(const f16x8*)&Wt[cf * 16 + l15][ks * 32 + g * 8];

  for (int t = blockIdx.x; t < NTILE; t += GGRID) {
    int rowbase = t * 128 + wv * 32;
    f32x4 acc[2][4];
#pragma unroll
    for (int i = 0; i < 2; i++)
#pragma unroll
      for (int j = 0; j < 4; j++) acc[i][j] = (f32x4){0.f, 0.f, 0.f, 0.f};

    int r0 = min(rowbase + l15, NN - 1);
    int r1 = min(rowbase + 16 + l15, NN - 1);
    const _Float16* p0 = (const _Float16*)X + (size_t)r0 * CHID + g * 8;
    const _Float16* p1 = (const _Float16*)X + (size_t)r1 * CHID + g * 8;

    f16x8 xa = *(const f16x8*)p0;
    f16x8 xb = *(const f16x8*)p1;

#pragma unroll
    for (int ks = 0; ks < 4; ks++) {
      f16x8 ca = xa, cb = xb;
      if (ks < 3) {
        int o = (ks + 1) * 32;
        xa = *(const f16x8*)(p0 + o);
        xb = *(const f16x8*)(p1 + o);
      }
#pragma unroll
      for (int cf = 0; cf < 4; cf++) {
        acc[0][cf] = __builtin_amdgcn_mfma_f32_16x16x32_f16(wf[cf][ks], ca, acc[0][cf], 0, 0, 0);
        acc[1][cf] = __builtin_amdgcn_mfma_f32_16x16x32_f16(wf[cf][ks], cb, acc[1][cf], 0, 0, 0);
      }
    }

#pragma unroll
    for (int rf = 0; rf < 2; rf++) {
      int row = rowbase + rf * 16 + l15;
      if (row < NN) {
        float dn = dinv[row];
#pragma unroll
        for (int cf = 0; cf < 4; cf++) {
          int col = cf * 16 + g * 4;
          __half2 h0 = __half2(__float2half(dn * acc[rf][cf][0]),
                               __float2half(dn * acc[rf][cf][1]));
          __half2 h1 = __half2(__float2half(dn * acc[rf][cf][2]),
                               __float2half(dn * acc[rf][cf][3]));
          uint2 s;
          s.x = *(unsigned*)&h0;
          s.y = *(unsigned*)&h1;
          *(uint2*)(G + (size_t)row * COUT + col) = s;
        }
      }
    }
  }
}

// accumulate 8 f16 channels (uint4) into 8 f32 (plain add)
#define ACC8(A, V)                                                  \
  {                                                                 \
    float2 f;                                                       \
    f = __half22float2(*(__half2*)&(V).x); A[0] += f.x; A[1] += f.y; \
    f = __half22float2(*(__half2*)&(V).y); A[2] += f.x; A[3] += f.y; \
    f = __half22float2(*(__half2*)&(V).z); A[4] += f.x; A[5] += f.y; \
    f = __half22float2(*(__half2*)&(V).w); A[6] += f.x; A[7] += f.y; \
  }

// ---------------- aggregation layer 1 (quarters of 16 lanes, R5-exact) ------
// Branchless padded csr (sentinel NN = zero row); lane owns 8 ch (16B uint4);
// 2 row-gathers in flight; g1 pre-scaled by dinv.
__global__ __launch_bounds__(256) void k_agg1(const __half* __restrict__ g,
                                              const int* __restrict__ rs,
                                              const int* __restrict__ re,
                                              const float* __restrict__ dinv,
                                              const int* __restrict__ csr,
                                              const float* __restrict__ b,
                                              __half* __restrict__ o) {
  int wid = (blockIdx.x * blockDim.x + threadIdx.x) >> 6;
  int lane = threadIdx.x & 63;
  if (wid >= NN) return;
  int q = lane >> 4, ql = lane & 15;
  const uint4* gp = (const uint4*)g;   // row = 16 uint4

  float aA[8] = {0.f, 0.f, 0.f, 0.f, 0.f, 0.f, 0.f, 0.f};
  float aB[8] = {0.f, 0.f, 0.f, 0.f, 0.f, 0.f, 0.f, 0.f};

  if (q == 0) {                         // self row (g pre-scaled by dinv)
    uint4 v = gp[(size_t)wid * 16 + ql];
    ACC8(aA, v);
  }

  int i0 = rs[wid], i1 = re[wid];       // padded range, multiple of 8
  for (int i = i0; i < i1; i += 8) {
    int sA = csr[i + q];                // 16-lane broadcast, L1-served
    int sB = csr[i + 4 + q];
    uint4 vA = gp[(size_t)sA * 16 + ql];
    uint4 vB = gp[(size_t)sB * 16 + ql];
    ACC8(aA, vA); ACC8(aB, vB);
  }

  float r[8];
#pragma unroll
  for (int c = 0; c < 8; c++) {
    float t = aA[c] + aB[c];
    t += __shfl_xor(t, 16);
    t += __shfl_xor(t, 32);
    r[c] = t;
  }
  if (q == 0) {
    float dn = dinv[wid];
    float4 b0 = *(const float4*)(b + 8 * ql);
    float4 b1 = *(const float4*)(b + 8 * ql + 4);
    __half2 h[4];
    h[0] = __half2(__float2half(fmaxf(fmaf(dn, r[0], b0.x), 0.f)),
                   __float2half(fmaxf(fmaf(dn, r[1], b0.y), 0.f)));
    h[1] = __half2(__float2half(fmaxf(fmaf(dn, r[2], b0.z), 0.f)),
                   __float2half(fmaxf(fmaf(dn, r[3], b0.w), 0.f)));
    h[2] = __half2(__float2half(fmaxf(fmaf(dn, r[4], b1.x), 0.f)),
                   __float2half(fmaxf(fmaf(dn, r[5], b1.y), 0.f)));
    h[3] = __half2(__float2half(fmaxf(fmaf(dn, r[6], b1.z), 0.f)),
                   __float2half(fmaxf(fmaf(dn, r[7], b1.w), 0.f)));
    *(uint4*)(o + (size_t)wid * CHID + 8 * ql) = *(uint4*)h;
  }
}

// ---------------- aggregation layer 2 (eighths of 8 lanes, R5-exact) -------
__global__ __launch_bounds__(256) void k_agg2(const __half* __restrict__ g,
                                              const int* __restrict__ rs,
                                              const int* __restrict__ re,
                                              const float* __restrict__ dinv,
                                              const int* __restrict__ csr,
                                              const float* __restrict__ b,
                                              float* __restrict__ o) {
  int wid = (blockIdx.x * blockDim.x + threadIdx.x) >> 6;
  int lane = threadIdx.x & 63;
  if (wid >= NN) return;
  int g8 = lane >> 3, gl = lane & 7;
  const uint4* gp = (const uint4*)g;   // row = 8 uint4

  float aA[8] = {0.f, 0.f, 0.f, 0.f, 0.f, 0.f, 0.f, 0.f};

  if (g8 == 0) {                        // self row (g2 pre-scaled)
    uint4 v = gp[(size_t)wid * 8 + gl];
    ACC8(aA, v);
  }

  int i0 = rs[wid], i1 = re[wid];       // padded range, multiple of 8
  for (int i = i0; i < i1; i += 8) {
    int s = csr[i + g8];                // 8-lane broadcast
    uint4 v = gp[(size_t)s * 8 + gl];
    ACC8(aA, v);
  }

  float r[8];
#pragma unroll
  for (int c = 0; c < 8; c++) {
    float t = aA[c];
    t += __shfl_xor(t, 8);
    t += __shfl_xor(t, 16);
    t += __shfl_xor(t, 32);
    r[c] = t;
  }
  if (g8 == 0) {
    float dn = dinv[wid];
    float4 b0 = *(const float4*)(b + 8 * gl);
    float4 b1 = *(const float4*)(b + 8 * gl + 4);
    float4 o0 = make_float4(fmaf(dn, r[0], b0.x), fmaf(dn, r[1], b0.y),
                            fmaf(dn, r[2], b0.z), fmaf(dn, r[3], b0.w));
    float4 o1v = make_float4(fmaf(dn, r[4], b1.x), fmaf(dn, r[5], b1.y),
                             fmaf(dn, r[6], b1.z), fmaf(dn, r[7], b1.w));
    *(float4*)(o + (size_t)wid * COUT + 8 * gl) = o0;
    *(float4*)(o + (size_t)wid * COUT + 8 * gl + 4) = o1v;
  }
}

// ---------------- launch ----------------

extern "C" void kernel_launch(void* const* d_in, const int* in_sizes, int n_in,
                              void* d_out, int out_size, void* d_ws, size_t ws_size,
                              hipStream_t stream) {
  const float* x  = (const float*)d_in[0];
  const int*   ei = (const int*)d_in[1];
  const float* W1 = (const float*)d_in[2];
  const float* b1 = (const float*)d_in[3];
  const float* W2 = (const float*)d_in[4];
  const float* b2 = (const float*)d_in[5];
  float* out = (float*)d_out;

  const int* esrc = ei;
  const int* edst = ei + NE;

  char* p = (char*)d_ws;
  __half* g1 = (__half*)p;    p += (size_t)(NN + 1) * CHID * 2;  // +zero row
  __half* o1 = (__half*)p;    p += (size_t)NN * CHID * 2;
  __half* g2 = (__half*)p;    p += (size_t)(NN + 1) * COUT * 2;  // +zero row
  int* rs  = (int*)p;         p += (size_t)NN * 4;
  int* re  = (int*)p;         p += (size_t)NN * 4;
  float* dinv = (float*)p;    p += (size_t)NN * 4;
  int* tab = (int*)p;         p += (size_t)NB * NBLK * 4;        // 200 KB
  int* bb  = (int*)p;         p += (size_t)(NB + 1) * 4;
  int* barr = (int*)p;        p += (size_t)NE * 4;               // 6.4 MB
  int* csr = (int*)p;         p += (size_t)(NE + NB * BPAD) * 4; // 9.6 MB

  // CSR build (two-level partition, padded)
  hipLaunchKernelGGL(k_passA, dim3(NBLK), dim3(512), 0, stream, edst, tab);
  hipLaunchKernelGGL(k_scan, dim3(1), dim3(512), 0, stream, tab, bb);
  hipLaunchKernelGGL(k_passB, dim3(NBLK), dim3(512), 0, stream, esrc, edst, tab, barr);
  hipLaunchKernelGGL(k_l2, dim3(NB), dim3(256), 0, stream, barr, bb, csr, rs, re,
                     dinv, g1, g2);

  // layer 1
  hipLaunchKernelGGL(k_gemm1, dim3(GGRID), dim3(256), 0, stream, x, W1, dinv, g1);
  hipLaunchKernelGGL(k_agg1, dim3((NN + 3) / 4), dim3(256), 0, stream,
                     g1, rs, re, dinv, csr, b1, o1);

  // layer 2
  hipLaunchKernelGGL(k_gemm2, dim3(GGRID), dim3(256), 0, stream, o1, W2, dinv, g2);
  hipLaunchKernelGGL(k_agg2, dim3((NN + 3) / 4), dim3(256), 0, stream,
                     g2, rs, re, dinv, csr, b2, out);
}

// Round 11
// 224.326 us; speedup vs baseline: 1.0416x; 1.0311x over previous
//
#include <hip/hip_runtime.h>
#include <hip/hip_fp16.h>

#define NN   100000
#define NE   1600000
#define CIN  128
#define CHID 128
#define COUT 64

// two-level CSR build
#define NPB  256                  // nodes per bucket (dst >> 8)
#define NB   391                  // ceil(NN / NPB)
#define NBLK 128                  // partition blocks
#define CHUNK ((NE + NBLK - 1) / NBLK)   // 12500
#define BPAD 2048                 // per-bucket padding slack (256 nodes * 8)

// MFMA types
typedef _Float16 f16x8 __attribute__((ext_vector_type(8)));
typedef float    f32x4 __attribute__((ext_vector_type(4)));

#define NTILE 782   // ceil(NN/128)
#define GGRID 512

// ---------------- zero sentinel rows ----------------
__global__ void k_zrow(__half* __restrict__ g1, __half* __restrict__ g2) {
  int t = threadIdx.x;
  if (t < 128) g1[(size_t)NN * CHID + t] = __float2half(0.f);
  if (t < 64)  g2[(size_t)NN * COUT + t] = __float2half(0.f);
}

// ---------------- pass A: per-(bucket,block) histogram ----------------
__global__ __launch_bounds__(512) void k_passA(const int* __restrict__ dst,
                                               int* __restrict__ tab) {
  __shared__ int hist[NB];
  int tid = threadIdx.x;
  for (int t = tid; t < NB; t += 512) hist[t] = 0;
  __syncthreads();
  int i0 = blockIdx.x * CHUNK;
  int i1 = min(i0 + CHUNK, NE);
  for (int i = i0 + tid; i < i1; i += 512)
    atomicAdd(&hist[((unsigned)dst[i]) >> 8], 1);
  __syncthreads();
  for (int t = tid; t < NB; t += 512)
    tab[t * NBLK + blockIdx.x] = hist[t];
}

// ---------------- bucket-total exclusive scan ----------------
__global__ __launch_bounds__(512) void k_bscan(const int* __restrict__ tab,
                                               int* __restrict__ bb) {
  __shared__ int s[512];
  int t = threadIdx.x;
  int v = 0;
  if (t < NB) {
    const int* row = tab + t * NBLK;
#pragma unroll 8
    for (int k = 0; k < NBLK; k++) v += row[k];
  }
  s[t] = v;
  __syncthreads();
  for (int off = 1; off < 512; off <<= 1) {
    int u = (t >= off) ? s[t - off] : 0;
    __syncthreads();
    s[t] += u;
    __syncthreads();
  }
  if (t < NB) bb[t] = s[t] - v;
  if (t == 0) bb[NB] = NE;
}

// ---------------- per-bucket block-offset scan ----------------
__global__ __launch_bounds__(128) void k_tabscan(int* __restrict__ tab,
                                                 const int* __restrict__ bb) {
  __shared__ int s[128];
  int b = blockIdx.x, t = threadIdx.x;
  int v = tab[b * NBLK + t];
  s[t] = v;
  __syncthreads();
  for (int off = 1; off < 128; off <<= 1) {
    int u = (t >= off) ? s[t - off] : 0;
    __syncthreads();
    s[t] += u;
    __syncthreads();
  }
  tab[b * NBLK + t] = bb[b] + s[t] - v;
}

// ---------------- pass B: scatter edges into bucket array ----------------
// entry = (src << 8) | (dst & 255);  src < 2^17 so this fits 25 bits
__global__ __launch_bounds__(512) void k_passB(const int* __restrict__ src,
                                               const int* __restrict__ dst,
                                               const int* __restrict__ tab,
                                               int* __restrict__ barr) {
  __shared__ int cur[NB];
  int tid = threadIdx.x;
  for (int t = tid; t < NB; t += 512) cur[t] = tab[t * NBLK + blockIdx.x];
  __syncthreads();
  int i0 = blockIdx.x * CHUNK;
  int i1 = min(i0 + CHUNK, NE);
  for (int i = i0 + tid; i < i1; i += 512) {
    int d = dst[i];
    unsigned b = ((unsigned)d) >> 8;
    int p = atomicAdd(&cur[b], 1);
    barr[p] = (src[i] << 8) | (d & 255);
  }
}

// ---------------- level 2: per-bucket -> padded csr, rs, re, dinv ----------
// Node ranges padded to multiples of 8; pad slots hold sentinel NN (zero row).
// Padded bucket base = bb[b] + b*BPAD (deterministic).
__global__ __launch_bounds__(256) void k_l2(const int* __restrict__ barr,
                                            const int* __restrict__ bb,
                                            int* __restrict__ csr,
                                            int* __restrict__ rs,
                                            int* __restrict__ re,
                                            float* __restrict__ dinv) {
  __shared__ int lcnt[NPB];
  __shared__ int lcur[NPB];
  int b = blockIdx.x, t = threadIdx.x;
  int e0 = bb[b], e1 = bb[b + 1];
  lcnt[t] = 0;
  __syncthreads();
  for (int i = e0 + t; i < e1; i += 256) atomicAdd(&lcnt[barr[i] & 255], 1);
  __syncthreads();
  int v = lcnt[t];
  int pv = (v + 7) & ~7;          // padded count
  lcur[t] = pv;
  __syncthreads();
  for (int off = 1; off < 256; off <<= 1) {
    int u = (t >= off) ? lcur[t - off] : 0;
    __syncthreads();
    lcur[t] += u;
    __syncthreads();
  }
  int pex = lcur[t] - pv;         // exclusive padded scan
  int start = e0 + b * BPAD + pex;
  int g = b * NPB + t;
  if (g < NN) {
    rs[g] = start;
    re[g] = start + pv;
    dinv[g] = rsqrtf((float)v + 1.0f);
  }
  __syncthreads();
  lcur[t] = start;                // scatter cursor
  // fill this node's pad slots with sentinel
  for (int k = v; k < pv; k++) csr[start + k] = NN;
  __syncthreads();
  for (int i = e0 + t; i < e1; i += 256) {
    int w = barr[i];
    int p = atomicAdd(&lcur[w & 255], 1);
    csr[p] = ((unsigned)w) >> 8;
  }
}

// ---------------- GEMM 1 (MFMA f16): G1[N,128] = f16(dinv*(X @ W1)) --------
__global__ __launch_bounds__(256, 2) void k_gemm1(const float* __restrict__ X,
                                                  const float* __restrict__ W,
                                                  const float* __restrict__ dinv,
                                                  __half* __restrict__ G) {
  __shared__ _Float16 Wt[128][128];   // [col][k], 32 KB
  int tid = threadIdx.x;
  for (int i = tid; i < 128 * 32; i += 256) {
    int k = i >> 5, c4 = (i & 31) << 2;
    float4 v = ((const float4*)W)[i];
    Wt[c4 + 0][k] = (_Float16)v.x;
    Wt[c4 + 1][k] = (_Float16)v.y;
    Wt[c4 + 2][k] = (_Float16)v.z;
    Wt[c4 + 3][k] = (_Float16)v.w;
  }
  __syncthreads();
  int wv = tid >> 6, lane = tid & 63;
  int l15 = lane & 15, g = lane >> 4;

  f16x8 wf[8][4];
#pragma unroll
  for (int cf = 0; cf < 8; cf++)
#pragma unroll
    for (int ks = 0; ks < 4; ks++)
      wf[cf][ks] = *(const f16x8*)&Wt[cf * 16 + l15][ks * 32 + g * 8];

  for (int t = blockIdx.x; t < NTILE; t += GGRID) {
    int rowbase = t * 128 + wv * 32;
    f32x4 acc[2][8];
#pragma unroll
    for (int i = 0; i < 2; i++)
#pragma unroll
      for (int j = 0; j < 8; j++) acc[i][j] = (f32x4){0.f, 0.f, 0.f, 0.f};

    int r0 = min(rowbase + l15, NN - 1);
    int r1 = min(rowbase + 16 + l15, NN - 1);
    const float* p0 = X + (size_t)r0 * CIN + g * 8;
    const float* p1 = X + (size_t)r1 * CIN + g * 8;

    float4 u0a = *(const float4*)p0, u0b = *(const float4*)(p0 + 4);
    float4 u1a = *(const float4*)p1, u1b = *(const float4*)(p1 + 4);

#pragma unroll
    for (int ks = 0; ks < 4; ks++) {
      f16x8 xa, xb;
      xa[0] = (_Float16)u0a.x; xa[1] = (_Float16)u0a.y;
      xa[2] = (_Float16)u0a.z; xa[3] = (_Float16)u0a.w;
      xa[4] = (_Float16)u0b.x; xa[5] = (_Float16)u0b.y;
      xa[6] = (_Float16)u0b.z; xa[7] = (_Float16)u0b.w;
      xb[0] = (_Float16)u1a.x; xb[1] = (_Float16)u1a.y;
      xb[2] = (_Float16)u1a.z; xb[3] = (_Float16)u1a.w;
      xb[4] = (_Float16)u1b.x; xb[5] = (_Float16)u1b.y;
      xb[6] = (_Float16)u1b.z; xb[7] = (_Float16)u1b.w;
      if (ks < 3) {
        int o = (ks + 1) * 32;
        u0a = *(const float4*)(p0 + o); u0b = *(const float4*)(p0 + o + 4);
        u1a = *(const float4*)(p1 + o); u1b = *(const float4*)(p1 + o + 4);
      }
#pragma unroll
      for (int cf = 0; cf < 8; cf++) {
        acc[0][cf] = __builtin_amdgcn_mfma_f32_16x16x32_f16(wf[cf][ks], xa, acc[0][cf], 0, 0, 0);
        acc[1][cf] = __builtin_amdgcn_mfma_f32_16x16x32_f16(wf[cf][ks], xb, acc[1][cf], 0, 0, 0);
      }
    }

#pragma unroll
    for (int rf = 0; rf < 2; rf++) {
      int row = rowbase + rf * 16 + l15;
      if (row < NN) {
        float dn = dinv[row];
#pragma unroll
        for (int cf = 0; cf < 8; cf++) {
          int col = cf * 16 + g * 4;
          __half2 h0 = __half2(__float2half(dn * acc[rf][cf][0]),
                               __float2half(dn * acc[rf][cf][1]));
          __half2 h1 = __half2(__float2half(dn * acc[rf][cf][2]),
                               __float2half(dn * acc[rf][cf][3]));
          uint2 s;
          s.x = *(unsigned*)&h0;
          s.y = *(unsigned*)&h1;
          *(uint2*)(G + (size_t)row * CHID + col) = s;
        }
      }
    }
  }
}

// ---------------- GEMM 2 (MFMA f16): G2[N,64] = f16(dinv*(O1 @ W2)) --------
__global__ __launch_bounds__(256, 2) void k_gemm2(const __half* __restrict__ X,
                                                  const float* __restrict__ W,
                                                  const float* __restrict__ dinv,
                                                  __half* __restrict__ G) {
  __shared__ _Float16 Wt[64][128];    // [col][k], 16 KB
  int tid = threadIdx.x;
  for (int i = tid; i < 128 * 16; i += 256) {
    int k = i >> 4, c4 = (i & 15) << 2;
    float4 v = ((const float4*)W)[i];
    Wt[c4 + 0][k] = (_Float16)v.x;
    Wt[c4 + 1][k] = (_Float16)v.y;
    Wt[c4 + 2][k] = (_Float16)v.z;
    Wt[c4 + 3][k] = (_Float16)v.w;
  }
  __syncthreads();
  int wv = tid >> 6, lane = tid & 63;
  int l15 = lane & 15, g = lane >> 4;

  f16x8 wf[4][4];
#pragma unroll
  for (int cf = 0; cf < 4; cf++)
#pragma unroll
    for (int ks = 0; ks < 4; ks++)
      wf[cf][ks] = *(const f16x8*)&Wt[cf * 16 + l15][ks * 32 + g * 8];

  for (int t = blockIdx.x; t < NTILE; t += GGRID) {
    int rowbase = t * 128 + wv * 32;
    f32x4 acc[2][4];
#pragma unroll
    for (int i = 0; i < 2; i++)
#pragma unroll
      for (int j = 0; j < 4; j++) acc[i][j] = (f32x4){0.f, 0.f, 0.f, 0.f};

    int r0 = min(rowbase + l15, NN - 1);
    int r1 = min(rowbase + 16 + l15, NN - 1);
    const _Float16* p0 = (const _Float16*)X + (size_t)r0 * CHID + g * 8;
    const _Float16* p1 = (const _Float16*)X + (size_t)r1 * CHID + g * 8;

    f16x8 xa = *(const f16x8*)p0;
    f16x8 xb = *(const f16x8*)p1;

#pragma unroll
    for (int ks = 0; ks < 4; ks++) {
      f16x8 ca = xa, cb = xb;
      if (ks < 3) {
        int o = (ks + 1) * 32;
        xa = *(const f16x8*)(p0 + o);
        xb = *(const f16x8*)(p1 + o);
      }
#pragma unroll
      for (int cf = 0; cf < 4; cf++) {
        acc[0][cf] = __builtin_amdgcn_mfma_f32_16x16x32_f16(wf[cf][ks], ca, acc[0][cf], 0, 0, 0);
        acc[1][cf] = __builtin_amdgcn_mfma_f32_16x16x32_f16(wf[cf][ks], cb, acc[1][cf], 0, 0, 0);
      }
    }

#pragma unroll
    for (int rf = 0; rf < 2; rf++) {
      int row = rowbase + rf * 16 + l15;
      if (row < NN) {
        float dn = dinv[row];
#pragma unroll
        for (int cf = 0; cf < 4; cf++) {
          int col = cf * 16 + g * 4;
          __half2 h0 = __half2(__float2half(dn * acc[rf][cf][0]),
                               __float2half(dn * acc[rf][cf][1]));
          __half2 h1 = __half2(__float2half(dn * acc[rf][cf][2]),
                               __float2half(dn * acc[rf][cf][3]));
          uint2 s;
          s.x = *(unsigned*)&h0;
          s.y = *(unsigned*)&h1;
          *(uint2*)(G + (size_t)row * COUT + col) = s;
        }
      }
    }
  }
}

// accumulate 8 f16 channels (uint4) into 8 f32
#define ACC8(A, V)                                                  \
  {                                                                 \
    float2 f;                                                       \
    f = __half22float2(*(__half2*)&(V).x); A[0] += f.x; A[1] += f.y; \
    f = __half22float2(*(__half2*)&(V).y); A[2] += f.x; A[3] += f.y; \
    f = __half22float2(*(__half2*)&(V).z); A[4] += f.x; A[5] += f.y; \
    f = __half22float2(*(__half2*)&(V).w); A[6] += f.x; A[7] += f.y; \
  }

// ---------------- aggregation layer 1 (quarters of 16 lanes) ----------------
// Branchless: padded csr (pad -> sentinel NN = zero row). Lane owns 8 ch
// (16B uint4); each 16-lane quarter gathers its own edge; 4 edges + 1 KB
// per load instruction; no shuffles in the loop.
__global__ __launch_bounds__(256) void k_agg1(const __half* __restrict__ g,
                                              const int* __restrict__ rs,
                                              const int* __restrict__ re,
                                              const float* __restrict__ dinv,
                                              const int* __restrict__ csr,
                                              const float* __restrict__ b,
                                              __half* __restrict__ o) {
  int wid = (blockIdx.x * blockDim.x + threadIdx.x) >> 6;
  int lane = threadIdx.x & 63;
  if (wid >= NN) return;
  int q = lane >> 4, ql = lane & 15;
  const uint4* gp = (const uint4*)g;   // row = 16 uint4

  float aA[8] = {0.f, 0.f, 0.f, 0.f, 0.f, 0.f, 0.f, 0.f};
  float aB[8] = {0.f, 0.f, 0.f, 0.f, 0.f, 0.f, 0.f, 0.f};

  if (q == 0) {                         // self row
    uint4 v = gp[(size_t)wid * 16 + ql];
    ACC8(aA, v);
  }

  int i0 = rs[wid], i1 = re[wid];       // padded range, multiple of 8
  for (int i = i0; i < i1; i += 8) {
    int sA = csr[i + q];                // 16-lane broadcast, L1-served
    int sB = csr[i + 4 + q];
    uint4 vA = gp[(size_t)sA * 16 + ql];
    uint4 vB = gp[(size_t)sB * 16 + ql];
    ACC8(aA, vA);
    ACC8(aB, vB);
  }

  float r[8];
#pragma unroll
  for (int c = 0; c < 8; c++) {
    float t = aA[c] + aB[c];
    t += __shfl_xor(t, 16);
    t += __shfl_xor(t, 32);
    r[c] = t;
  }
  if (q == 0) {
    float dn = dinv[wid];
    float4 b0 = *(const float4*)(b + 8 * ql);
    float4 b1 = *(const float4*)(b + 8 * ql + 4);
    __half2 h[4];
    h[0] = __half2(__float2half(fmaxf(fmaf(dn, r[0], b0.x), 0.f)),
                   __float2half(fmaxf(fmaf(dn, r[1], b0.y), 0.f)));
    h[1] = __half2(__float2half(fmaxf(fmaf(dn, r[2], b0.z), 0.f)),
                   __float2half(fmaxf(fmaf(dn, r[3], b0.w), 0.f)));
    h[2] = __half2(__float2half(fmaxf(fmaf(dn, r[4], b1.x), 0.f)),
                   __float2half(fmaxf(fmaf(dn, r[5], b1.y), 0.f)));
    h[3] = __half2(__float2half(fmaxf(fmaf(dn, r[6], b1.z), 0.f)),
                   __float2half(fmaxf(fmaf(dn, r[7], b1.w), 0.f)));
    *(uint4*)(o + (size_t)wid * CHID + 8 * ql) = *(uint4*)h;
  }
}

// ---------------- aggregation layer 2 (eighths of 8 lanes) ------------------
// Row = 8 uint4; each 8-lane group gathers its own edge; 8 edges + 1 KB per
// load instruction. fp32 output.
__global__ __launch_bounds__(256) void k_agg2(const __half* __restrict__ g,
                                              const int* __restrict__ rs,
                                              const int* __restrict__ re,
                                              const float* __restrict__ dinv,
                                              const int* __restrict__ csr,
                                              const float* __restrict__ b,
                                              float* __restrict__ o) {
  int wid = (blockIdx.x * blockDim.x + threadIdx.x) >> 6;
  int lane = threadIdx.x & 63;
  if (wid >= NN) return;
  int g8 = lane >> 3, gl = lane & 7;
  const uint4* gp = (const uint4*)g;   // row = 8 uint4

  float aA[8] = {0.f, 0.f, 0.f, 0.f, 0.f, 0.f, 0.f, 0.f};

  if (g8 == 0) {                        // self row
    uint4 v = gp[(size_t)wid * 8 + gl];
    ACC8(aA, v);
  }

  int i0 = rs[wid], i1 = re[wid];       // padded range, multiple of 8
  for (int i = i0; i < i1; i += 8) {
    int s = csr[i + g8];                // 8-lane broadcast
    uint4 v = gp[(size_t)s * 8 + gl];
    ACC8(aA, v);
  }

  float r[8];
#pragma unroll
  for (int c = 0; c < 8; c++) {
    float t = aA[c];
    t += __shfl_xor(t, 8);
    t += __shfl_xor(t, 16);
    t += __shfl_xor(t, 32);
    r[c] = t;
  }
  if (g8 == 0) {
    float dn = dinv[wid];
    float4 b0 = *(const float4*)(b + 8 * gl);
    float4 b1 = *(const float4*)(b + 8 * gl + 4);
    float4 o0 = make_float4(fmaf(dn, r[0], b0.x), fmaf(dn, r[1], b0.y),
                            fmaf(dn, r[2], b0.z), fmaf(dn, r[3], b0.w));
    float4 o1v = make_float4(fmaf(dn, r[4], b1.x), fmaf(dn, r[5], b1.y),
                             fmaf(dn, r[6], b1.z), fmaf(dn, r[7], b1.w));
    *(float4*)(o + (size_t)wid * COUT + 8 * gl) = o0;
    *(float4*)(o + (size_t)wid * COUT + 8 * gl + 4) = o1v;
  }
}

// ---------------- launch ----------------

extern "C" void kernel_launch(void* const* d_in, const int* in_sizes, int n_in,
                              void* d_out, int out_size, void* d_ws, size_t ws_size,
                              hipStream_t stream) {
  const float* x  = (const float*)d_in[0];
  const int*   ei = (const int*)d_in[1];
  const float* W1 = (const float*)d_in[2];
  const float* b1 = (const float*)d_in[3];
  const float* W2 = (const float*)d_in[4];
  const float* b2 = (const float*)d_in[5];
  float* out = (float*)d_out;

  const int* esrc = ei;
  const int* edst = ei + NE;

  char* p = (char*)d_ws;
  __half* g1 = (__half*)p;    p += (size_t)(NN + 1) * CHID * 2;  // +zero row
  __half* o1 = (__half*)p;    p += (size_t)NN * CHID * 2;
  __half* g2 = (__half*)p;    p += (size_t)(NN + 1) * COUT * 2;  // +zero row
  int* rs  = (int*)p;         p += (size_t)NN * 4;
  int* re  = (int*)p;         p += (size_t)NN * 4;
  float* dinv = (float*)p;    p += (size_t)NN * 4;
  int* tab = (int*)p;         p += (size_t)NB * NBLK * 4;        // 200 KB
  int* bb  = (int*)p;         p += (size_t)(NB + 1) * 4;
  int* barr = (int*)p;        p += (size_t)NE * 4;               // 6.4 MB
  int* csr = (int*)p;         p += (size_t)(NE + NB * BPAD) * 4; // 9.6 MB

  // zero sentinel rows (read by padded-slot gathers)
  hipLaunchKernelGGL(k_zrow, dim3(1), dim3(128), 0, stream, g1, g2);

  // CSR build (two-level partition, padded, write-combine friendly)
  hipLaunchKernelGGL(k_passA, dim3(NBLK), dim3(512), 0, stream, edst, tab);
  hipLaunchKernelGGL(k_bscan, dim3(1), dim3(512), 0, stream, tab, bb);
  hipLaunchKernelGGL(k_tabscan, dim3(NB), dim3(128), 0, stream, tab, bb);
  hipLaunchKernelGGL(k_passB, dim3(NBLK), dim3(512), 0, stream, esrc, edst, tab, barr);
  hipLaunchKernelGGL(k_l2, dim3(NB), dim3(256), 0, stream, barr, bb, csr, rs, re, dinv);

  // layer 1
  hipLaunchKernelGGL(k_gemm1, dim3(GGRID), dim3(256), 0, stream, x, W1, dinv, g1);
  hipLaunchKernelGGL(k_agg1, dim3((NN + 3) / 4), dim3(256), 0, stream, g1, rs, re, dinv, csr, b1, o1);

  // layer 2
  hipLaunchKernelGGL(k_gemm2, dim3(GGRID), dim3(256), 0, stream, o1, W2, dinv, g2);
  hipLaunchKernelGGL(k_agg2, dim3((NN + 3) / 4), dim3(256), 0, stream, g2, rs, re, dinv, csr, b2, out);
}

// Round 12
// 223.727 us; speedup vs baseline: 1.0444x; 1.0027x over previous
//
#include <hip/hip_runtime.h>
#include <hip/hip_fp16.h>

#define NN   100000
#define NE   1600000
#define CIN  128
#define CHID 128
#define COUT 64

// two-level CSR build
#define NPB  256                  // nodes per bucket (dst >> 8)
#define NB   391                  // ceil(NN / NPB)
#define NBLK 128                  // partition blocks
#define CHUNK ((NE + NBLK - 1) / NBLK)   // 12500
#define BPAD 2048                 // per-bucket padding slack (256 nodes * 8)

// MFMA types
typedef _Float16 f16x8 __attribute__((ext_vector_type(8)));
typedef float    f32x4 __attribute__((ext_vector_type(4)));

#define NTILE 782   // ceil(NN/128)
#define GGRID 512

// ---------------- zero sentinel rows ----------------
__global__ void k_zrow(__half* __restrict__ g1, __half* __restrict__ g2) {
  int t = threadIdx.x;
  if (t < 128) g1[(size_t)NN * CHID + t] = __float2half(0.f);
  if (t < 64)  g2[(size_t)NN * COUT + t] = __float2half(0.f);
}

// ---------------- pass A: per-(bucket,block) histogram ----------------
__global__ __launch_bounds__(512) void k_passA(const int* __restrict__ dst,
                                               int* __restrict__ tab) {
  __shared__ int hist[NB];
  int tid = threadIdx.x;
  for (int t = tid; t < NB; t += 512) hist[t] = 0;
  __syncthreads();
  int i0 = blockIdx.x * CHUNK;
  int i1 = min(i0 + CHUNK, NE);
  for (int i = i0 + tid; i < i1; i += 512)
    atomicAdd(&hist[((unsigned)dst[i]) >> 8], 1);
  __syncthreads();
  for (int t = tid; t < NB; t += 512)
    tab[t * NBLK + blockIdx.x] = hist[t];
}

// ---------------- bucket-total exclusive scan ----------------
__global__ __launch_bounds__(512) void k_bscan(const int* __restrict__ tab,
                                               int* __restrict__ bb) {
  __shared__ int s[512];
  int t = threadIdx.x;
  int v = 0;
  if (t < NB) {
    const int* row = tab + t * NBLK;
#pragma unroll 8
    for (int k = 0; k < NBLK; k++) v += row[k];
  }
  s[t] = v;
  __syncthreads();
  for (int off = 1; off < 512; off <<= 1) {
    int u = (t >= off) ? s[t - off] : 0;
    __syncthreads();
    s[t] += u;
    __syncthreads();
  }
  if (t < NB) bb[t] = s[t] - v;
  if (t == 0) bb[NB] = NE;
}

// ---------------- per-bucket block-offset scan ----------------
__global__ __launch_bounds__(128) void k_tabscan(int* __restrict__ tab,
                                                 const int* __restrict__ bb) {
  __shared__ int s[128];
  int b = blockIdx.x, t = threadIdx.x;
  int v = tab[b * NBLK + t];
  s[t] = v;
  __syncthreads();
  for (int off = 1; off < 128; off <<= 1) {
    int u = (t >= off) ? s[t - off] : 0;
    __syncthreads();
    s[t] += u;
    __syncthreads();
  }
  tab[b * NBLK + t] = bb[b] + s[t] - v;
}

// ---------------- pass B: scatter edges into bucket array ----------------
// entry = (src << 8) | (dst & 255);  src < 2^17 so this fits 25 bits
__global__ __launch_bounds__(512) void k_passB(const int* __restrict__ src,
                                               const int* __restrict__ dst,
                                               const int* __restrict__ tab,
                                               int* __restrict__ barr) {
  __shared__ int cur[NB];
  int tid = threadIdx.x;
  for (int t = tid; t < NB; t += 512) cur[t] = tab[t * NBLK + blockIdx.x];
  __syncthreads();
  int i0 = blockIdx.x * CHUNK;
  int i1 = min(i0 + CHUNK, NE);
  for (int i = i0 + tid; i < i1; i += 512) {
    int d = dst[i];
    unsigned b = ((unsigned)d) >> 8;
    int p = atomicAdd(&cur[b], 1);
    barr[p] = (src[i] << 8) | (d & 255);
  }
}

// ---------------- level 2: per-bucket -> padded csr, rs, re, dinv ----------
// Node ranges padded to multiples of 8; pad slots hold sentinel NN (zero row).
// Padded bucket base = bb[b] + b*BPAD (deterministic).
__global__ __launch_bounds__(256) void k_l2(const int* __restrict__ barr,
                                            const int* __restrict__ bb,
                                            int* __restrict__ csr,
                                            int* __restrict__ rs,
                                            int* __restrict__ re,
                                            float* __restrict__ dinv) {
  __shared__ int lcnt[NPB];
  __shared__ int lcur[NPB];
  int b = blockIdx.x, t = threadIdx.x;
  int e0 = bb[b], e1 = bb[b + 1];
  lcnt[t] = 0;
  __syncthreads();
  for (int i = e0 + t; i < e1; i += 256) atomicAdd(&lcnt[barr[i] & 255], 1);
  __syncthreads();
  int v = lcnt[t];
  int pv = (v + 7) & ~7;          // padded count
  lcur[t] = pv;
  __syncthreads();
  for (int off = 1; off < 256; off <<= 1) {
    int u = (t >= off) ? lcur[t - off] : 0;
    __syncthreads();
    lcur[t] += u;
    __syncthreads();
  }
  int pex = lcur[t] - pv;         // exclusive padded scan
  int start = e0 + b * BPAD + pex;
  int g = b * NPB + t;
  if (g < NN) {
    rs[g] = start;
    re[g] = start + pv;
    dinv[g] = rsqrtf((float)v + 1.0f);
  }
  __syncthreads();
  lcur[t] = start;                // scatter cursor
  // fill this node's pad slots with sentinel
  for (int k = v; k < pv; k++) csr[start + k] = NN;
  __syncthreads();
  for (int i = e0 + t; i < e1; i += 256) {
    int w = barr[i];
    int p = atomicAdd(&lcur[w & 255], 1);
    csr[p] = ((unsigned)w) >> 8;
  }
}

// ---------------- GEMM 1 (MFMA f16): G1[N,128] = f16(dinv*(X @ W1)) --------
__global__ __launch_bounds__(256, 2) void k_gemm1(const float* __restrict__ X,
                                                  const float* __restrict__ W,
                                                  const float* __restrict__ dinv,
                                                  __half* __restrict__ G) {
  __shared__ _Float16 Wt[128][128];   // [col][k], 32 KB
  int tid = threadIdx.x;
  for (int i = tid; i < 128 * 32; i += 256) {
    int k = i >> 5, c4 = (i & 31) << 2;
    float4 v = ((const float4*)W)[i];
    Wt[c4 + 0][k] = (_Float16)v.x;
    Wt[c4 + 1][k] = (_Float16)v.y;
    Wt[c4 + 2][k] = (_Float16)v.z;
    Wt[c4 + 3][k] = (_Float16)v.w;
  }
  __syncthreads();
  int wv = tid >> 6, lane = tid & 63;
  int l15 = lane & 15, g = lane >> 4;

  f16x8 wf[8][4];
#pragma unroll
  for (int cf = 0; cf < 8; cf++)
#pragma unroll
    for (int ks = 0; ks < 4; ks++)
      wf[cf][ks] = *(const f16x8*)&Wt[cf * 16 + l15][ks * 32 + g * 8];

  for (int t = blockIdx.x; t < NTILE; t += GGRID) {
    int rowbase = t * 128 + wv * 32;
    f32x4 acc[2][8];
#pragma unroll
    for (int i = 0; i < 2; i++)
#pragma unroll
      for (int j = 0; j < 8; j++) acc[i][j] = (f32x4){0.f, 0.f, 0.f, 0.f};

    int r0 = min(rowbase + l15, NN - 1);
    int r1 = min(rowbase + 16 + l15, NN - 1);
    const float* p0 = X + (size_t)r0 * CIN + g * 8;
    const float* p1 = X + (size_t)r1 * CIN + g * 8;

    float4 u0a = *(const float4*)p0, u0b = *(const float4*)(p0 + 4);
    float4 u1a = *(const float4*)p1, u1b = *(const float4*)(p1 + 4);

#pragma unroll
    for (int ks = 0; ks < 4; ks++) {
      f16x8 xa, xb;
      xa[0] = (_Float16)u0a.x; xa[1] = (_Float16)u0a.y;
      xa[2] = (_Float16)u0a.z; xa[3] = (_Float16)u0a.w;
      xa[4] = (_Float16)u0b.x; xa[5] = (_Float16)u0b.y;
      xa[6] = (_Float16)u0b.z; xa[7] = (_Float16)u0b.w;
      xb[0] = (_Float16)u1a.x; xb[1] = (_Float16)u1a.y;
      xb[2] = (_Float16)u1a.z; xb[3] = (_Float16)u1a.w;
      xb[4] = (_Float16)u1b.x; xb[5] = (_Float16)u1b.y;
      xb[6] = (_Float16)u1b.z; xb[7] = (_Float16)u1b.w;
      if (ks < 3) {
        int o = (ks + 1) * 32;
        u0a = *(const float4*)(p0 + o); u0b = *(const float4*)(p0 + o + 4);
        u1a = *(const float4*)(p1 + o); u1b = *(const float4*)(p1 + o + 4);
      }
#pragma unroll
      for (int cf = 0; cf < 8; cf++) {
        acc[0][cf] = __builtin_amdgcn_mfma_f32_16x16x32_f16(wf[cf][ks], xa, acc[0][cf], 0, 0, 0);
        acc[1][cf] = __builtin_amdgcn_mfma_f32_16x16x32_f16(wf[cf][ks], xb, acc[1][cf], 0, 0, 0);
      }
    }

#pragma unroll
    for (int rf = 0; rf < 2; rf++) {
      int row = rowbase + rf * 16 + l15;
      if (row < NN) {
        float dn = dinv[row];
#pragma unroll
        for (int cf = 0; cf < 8; cf++) {
          int col = cf * 16 + g * 4;
          __half2 h0 = __half2(__float2half(dn * acc[rf][cf][0]),
                               __float2half(dn * acc[rf][cf][1]));
          __half2 h1 = __half2(__float2half(dn * acc[rf][cf][2]),
                               __float2half(dn * acc[rf][cf][3]));
          uint2 s;
          s.x = *(unsigned*)&h0;
          s.y = *(unsigned*)&h1;
          *(uint2*)(G + (size_t)row * CHID + col) = s;
        }
      }
    }
  }
}

// ---------------- GEMM 2 (MFMA f16): G2[N,64] = f16(dinv*(O1 @ W2)) --------
__global__ __launch_bounds__(256, 2) void k_gemm2(const __half* __restrict__ X,
                                                  const float* __restrict__ W,
                                                  const float* __restrict__ dinv,
                                                  __half* __restrict__ G) {
  __shared__ _Float16 Wt[64][128];    // [col][k], 16 KB
  int tid = threadIdx.x;
  for (int i = tid; i < 128 * 16; i += 256) {
    int k = i >> 4, c4 = (i & 15) << 2;
    float4 v = ((const float4*)W)[i];
    Wt[c4 + 0][k] = (_Float16)v.x;
    Wt[c4 + 1][k] = (_Float16)v.y;
    Wt[c4 + 2][k] = (_Float16)v.z;
    Wt[c4 + 3][k] = (_Float16)v.w;
  }
  __syncthreads();
  int wv = tid >> 6, lane = tid & 63;
  int l15 = lane & 15, g = lane >> 4;

  f16x8 wf[4][4];
#pragma unroll
  for (int cf = 0; cf < 4; cf++)
#pragma unroll
    for (int ks = 0; ks < 4; ks++)
      wf[cf][ks] = *(const f16x8*)&Wt[cf * 16 + l15][ks * 32 + g * 8];

  for (int t = blockIdx.x; t < NTILE; t += GGRID) {
    int rowbase = t * 128 + wv * 32;
    f32x4 acc[2][4];
#pragma unroll
    for (int i = 0; i < 2; i++)
#pragma unroll
      for (int j = 0; j < 4; j++) acc[i][j] = (f32x4){0.f, 0.f, 0.f, 0.f};

    int r0 = min(rowbase + l15, NN - 1);
    int r1 = min(rowbase + 16 + l15, NN - 1);
    const _Float16* p0 = (const _Float16*)X + (size_t)r0 * CHID + g * 8;
    const _Float16* p1 = (const _Float16*)X + (size_t)r1 * CHID + g * 8;

    f16x8 xa = *(const f16x8*)p0;
    f16x8 xb = *(const f16x8*)p1;

#pragma unroll
    for (int ks = 0; ks < 4; ks++) {
      f16x8 ca = xa, cb = xb;
      if (ks < 3) {
        int o = (ks + 1) * 32;
        xa = *(const f16x8*)(p0 + o);
        xb = *(const f16x8*)(p1 + o);
      }
#pragma unroll
      for (int cf = 0; cf < 4; cf++) {
        acc[0][cf] = __builtin_amdgcn_mfma_f32_16x16x32_f16(wf[cf][ks], ca, acc[0][cf], 0, 0, 0);
        acc[1][cf] = __builtin_amdgcn_mfma_f32_16x16x32_f16(wf[cf][ks], cb, acc[1][cf], 0, 0, 0);
      }
    }

#pragma unroll
    for (int rf = 0; rf < 2; rf++) {
      int row = rowbase + rf * 16 + l15;
      if (row < NN) {
        float dn = dinv[row];
#pragma unroll
        for (int cf = 0; cf < 4; cf++) {
          int col = cf * 16 + g * 4;
          __half2 h0 = __half2(__float2half(dn * acc[rf][cf][0]),
                               __float2half(dn * acc[rf][cf][1]));
          __half2 h1 = __half2(__float2half(dn * acc[rf][cf][2]),
                               __float2half(dn * acc[rf][cf][3]));
          uint2 s;
          s.x = *(unsigned*)&h0;
          s.y = *(unsigned*)&h1;
          *(uint2*)(G + (size_t)row * COUT + col) = s;
        }
      }
    }
  }
}

// accumulate 8 f16 channels (uint4) into 8 f32
#define ACC8(A, V)                                                  \
  {                                                                 \
    float2 f;                                                       \
    f = __half22float2(*(__half2*)&(V).x); A[0] += f.x; A[1] += f.y; \
    f = __half22float2(*(__half2*)&(V).y); A[2] += f.x; A[3] += f.y; \
    f = __half22float2(*(__half2*)&(V).z); A[4] += f.x; A[5] += f.y; \
    f = __half22float2(*(__half2*)&(V).w); A[6] += f.x; A[7] += f.y; \
  }

// ---------------- aggregation layer 1 (quarters of 16 lanes) ----------------
// Branchless: padded csr (pad -> sentinel NN = zero row). Lane owns 8 ch
// (16B uint4); each 16-lane quarter gathers its own edge; 4 edges + 1 KB
// per load instruction; no shuffles in the loop.
__global__ __launch_bounds__(256) void k_agg1(const __half* __restrict__ g,
                                              const int* __restrict__ rs,
                                              const int* __restrict__ re,
                                              const float* __restrict__ dinv,
                                              const int* __restrict__ csr,
                                              const float* __restrict__ b,
                                              __half* __restrict__ o) {
  int wid = (blockIdx.x * blockDim.x + threadIdx.x) >> 6;
  int lane = threadIdx.x & 63;
  if (wid >= NN) return;
  int q = lane >> 4, ql = lane & 15;
  const uint4* gp = (const uint4*)g;   // row = 16 uint4

  float aA[8] = {0.f, 0.f, 0.f, 0.f, 0.f, 0.f, 0.f, 0.f};
  float aB[8] = {0.f, 0.f, 0.f, 0.f, 0.f, 0.f, 0.f, 0.f};

  if (q == 0) {                         // self row
    uint4 v = gp[(size_t)wid * 16 + ql];
    ACC8(aA, v);
  }

  int i0 = rs[wid], i1 = re[wid];       // padded range, multiple of 8
  for (int i = i0; i < i1; i += 8) {
    int sA = csr[i + q];                // 16-lane broadcast, L1-served
    int sB = csr[i + 4 + q];
    uint4 vA = gp[(size_t)sA * 16 + ql];
    uint4 vB = gp[(size_t)sB * 16 + ql];
    ACC8(aA, vA);
    ACC8(aB, vB);
  }

  float r[8];
#pragma unroll
  for (int c = 0; c < 8; c++) {
    float t = aA[c] + aB[c];
    t += __shfl_xor(t, 16);
    t += __shfl_xor(t, 32);
    r[c] = t;
  }
  if (q == 0) {
    float dn = dinv[wid];
    float4 b0 = *(const float4*)(b + 8 * ql);
    float4 b1 = *(const float4*)(b + 8 * ql + 4);
    __half2 h[4];
    h[0] = __half2(__float2half(fmaxf(fmaf(dn, r[0], b0.x), 0.f)),
                   __float2half(fmaxf(fmaf(dn, r[1], b0.y), 0.f)));
    h[1] = __half2(__float2half(fmaxf(fmaf(dn, r[2], b0.z), 0.f)),
                   __float2half(fmaxf(fmaf(dn, r[3], b0.w), 0.f)));
    h[2] = __half2(__float2half(fmaxf(fmaf(dn, r[4], b1.x), 0.f)),
                   __float2half(fmaxf(fmaf(dn, r[5], b1.y), 0.f)));
    h[3] = __half2(__float2half(fmaxf(fmaf(dn, r[6], b1.z), 0.f)),
                   __float2half(fmaxf(fmaf(dn, r[7], b1.w), 0.f)));
    *(uint4*)(o + (size_t)wid * CHID + 8 * ql) = *(uint4*)h;
  }
}

// ---------------- aggregation layer 2 (eighths of 8 lanes) ------------------
// Row = 8 uint4; each 8-lane group gathers its own edge; 8 edges + 1 KB per
// load instruction. fp32 output.
__global__ __launch_bounds__(256) void k_agg2(const __half* __restrict__ g,
                                              const int* __restrict__ rs,
                                              const int* __restrict__ re,
                                              const float* __restrict__ dinv,
                                              const int* __restrict__ csr,
                                              const float* __restrict__ b,
                                              float* __restrict__ o) {
  int wid = (blockIdx.x * blockDim.x + threadIdx.x) >> 6;
  int lane = threadIdx.x & 63;
  if (wid >= NN) return;
  int g8 = lane >> 3, gl = lane & 7;
  const uint4* gp = (const uint4*)g;   // row = 8 uint4

  float aA[8] = {0.f, 0.f, 0.f, 0.f, 0.f, 0.f, 0.f, 0.f};

  if (g8 == 0) {                        // self row
    uint4 v = gp[(size_t)wid * 8 + gl];
    ACC8(aA, v);
  }

  int i0 = rs[wid], i1 = re[wid];       // padded range, multiple of 8
  for (int i = i0; i < i1; i += 8) {
    int s = csr[i + g8];                // 8-lane broadcast
    uint4 v = gp[(size_t)s * 8 + gl];
    ACC8(aA, v);
  }

  float r[8];
#pragma unroll
  for (int c = 0; c < 8; c++) {
    float t = aA[c];
    t += __shfl_xor(t, 8);
    t += __shfl_xor(t, 16);
    t += __shfl_xor(t, 32);
    r[c] = t;
  }
  if (g8 == 0) {
    float dn = dinv[wid];
    float4 b0 = *(const float4*)(b + 8 * gl);
    float4 b1 = *(const float4*)(b + 8 * gl + 4);
    float4 o0 = make_float4(fmaf(dn, r[0], b0.x), fmaf(dn, r[1], b0.y),
                            fmaf(dn, r[2], b0.z), fmaf(dn, r[3], b0.w));
    float4 o1v = make_float4(fmaf(dn, r[4], b1.x), fmaf(dn, r[5], b1.y),
                             fmaf(dn, r[6], b1.z), fmaf(dn, r[7], b1.w));
    *(float4*)(o + (size_t)wid * COUT + 8 * gl) = o0;
    *(float4*)(o + (size_t)wid * COUT + 8 * gl + 4) = o1v;
  }
}

// ---------------- launch ----------------

extern "C" void kernel_launch(void* const* d_in, const int* in_sizes, int n_in,
                              void* d_out, int out_size, void* d_ws, size_t ws_size,
                              hipStream_t stream) {
  const float* x  = (const float*)d_in[0];
  const int*   ei = (const int*)d_in[1];
  const float* W1 = (const float*)d_in[2];
  const float* b1 = (const float*)d_in[3];
  const float* W2 = (const float*)d_in[4];
  const float* b2 = (const float*)d_in[5];
  float* out = (float*)d_out;

  const int* esrc = ei;
  const int* edst = ei + NE;

  char* p = (char*)d_ws;
  __half* g1 = (__half*)p;    p += (size_t)(NN + 1) * CHID * 2;  // +zero row
  __half* o1 = (__half*)p;    p += (size_t)NN * CHID * 2;
  __half* g2 = (__half*)p;    p += (size_t)(NN + 1) * COUT * 2;  // +zero row
  int* rs  = (int*)p;         p += (size_t)NN * 4;
  int* re  = (int*)p;         p += (size_t)NN * 4;
  float* dinv = (float*)p;    p += (size_t)NN * 4;
  int* tab = (int*)p;         p += (size_t)NB * NBLK * 4;        // 200 KB
  int* bb  = (int*)p;         p += (size_t)(NB + 1) * 4;
  int* barr = (int*)p;        p += (size_t)NE * 4;               // 6.4 MB
  int* csr = (int*)p;         p += (size_t)(NE + NB * BPAD) * 4; // 9.6 MB

  // zero sentinel rows (read by padded-slot gathers)
  hipLaunchKernelGGL(k_zrow, dim3(1), dim3(128), 0, stream, g1, g2);

  // CSR build (two-level partition, padded, write-combine friendly)
  hipLaunchKernelGGL(k_passA, dim3(NBLK), dim3(512), 0, stream, edst, tab);
  hipLaunchKernelGGL(k_bscan, dim3(1), dim3(512), 0, stream, tab, bb);
  hipLaunchKernelGGL(k_tabscan, dim3(NB), dim3(128), 0, stream, tab, bb);
  hipLaunchKernelGGL(k_passB, dim3(NBLK), dim3(512), 0, stream, esrc, edst, tab, barr);
  hipLaunchKernelGGL(k_l2, dim3(NB), dim3(256), 0, stream, barr, bb, csr, rs, re, dinv);

  // layer 1
  hipLaunchKernelGGL(k_gemm1, dim3(GGRID), dim3(256), 0, stream, x, W1, dinv, g1);
  hipLaunchKernelGGL(k_agg1, dim3((NN + 3) / 4), dim3(256), 0, stream, g1, rs, re, dinv, csr, b1, o1);

  // layer 2
  hipLaunchKernelGGL(k_gemm2, dim3(GGRID), dim3(256), 0, stream, o1, W2, dinv, g2);
  hipLaunchKernelGGL(k_agg2, dim3((NN + 3) / 4), dim3(256), 0, stream, g2, rs, re, dinv, csr, b2, out);
}